// Round 11
// baseline (1062.788 us; speedup 1.0000x reference)
//
#include <hip/hip_runtime.h>
#include <cstdint>

#define NB 8
#define CIN 1024
#define HDIM 50
#define WDIM 50
#define COUT 512
#define NA 9
#define NANCH (HDIM*WDIM*NA)   /* 22500 */
#define PRE_N 2000
#define POST_N 100

typedef __attribute__((ext_vector_type(8))) short bf16x8;
typedef __attribute__((ext_vector_type(4))) float f32x4;
typedef __attribute__((ext_vector_type(16))) float f32x16;
typedef __attribute__((ext_vector_type(8))) unsigned short ushort8v;

// ---------------- workspace layout (bytes) ----------------
// t planes (bf16 hi/lo) in proj-A-frag order: [pxblk157][cchunk16][mf8][q4][pxl16][j8]
constexpr size_t TPLANE    = 20578304;                   // 157*16*4096 shorts * 2B
constexpr size_t OFF_TPH   = 0;
constexpr size_t OFF_TPL   = 20578304;
constexpr size_t OFF_BOXES = 41156608;                   // 8*22500*4 f32
constexpr size_t OFF_KEYS  = 44036608;                   // 8*22500 u64
constexpr size_t OFF_TBOX  = 45476608;                   // 8*2000*4 f32
constexpr size_t OFF_TS    = 45732608;                   // 8*2000 f32
constexpr size_t OFF_SUP   = 45796608;                   // 8*2000*32 u64
// feature planes, flat-padded-pixel layout: [b8][cic64][lk2][q2976][ci8] bf16
//   q = p' + 53, p' = rr*52+cc on the 52x52 zero-padded grid (rr,cc in 0..51)
constexpr size_t QDIM      = 2976;                       // covers q up to 2975 (stage max 2975)
constexpr size_t PLSTRIDE  = QDIM * 8;                   // shorts per (b,cic,lk) = 23808
constexpr size_t PPLANE    = 48758784;                   // 8*64*2*23808*2B
constexpr size_t OFF_PH    = 49892864;
constexpr size_t OFF_PL    = OFF_PH + PPLANE;            // 98,651,648
// weight planes: [cot8][cic64][tap9][lk2][co64][ci8] bf16
constexpr size_t WPLANE    = 9437184;
constexpr size_t OFF_WH    = 147410432;
constexpr size_t OFF_WL    = OFF_WH + WPLANE;            // end ~166.3 MB

__device__ __forceinline__ void split2bf16(float v, unsigned short &hi, unsigned short &lo) {
    unsigned int u = __float_as_uint(v);
    unsigned int r = u + 0x7FFFu + ((u >> 16) & 1u);
    hi = (unsigned short)(r >> 16);
    float hf = __uint_as_float(((unsigned int)hi) << 16);
    float lf = v - hf;
    unsigned int u2 = __float_as_uint(lf);
    unsigned int r2 = u2 + 0x7FFFu + ((u2 >> 16) & 1u);
    lo = (unsigned short)(r2 >> 16);
}

__device__ __forceinline__ void gl_lds(const unsigned short* g, unsigned short* l) {
    __builtin_amdgcn_global_load_lds(
        (const __attribute__((address_space(1))) unsigned int*)(const void*)g,
        (__attribute__((address_space(3))) unsigned int*)(void*)l,
        16, 0, 0);
}

// ---------------- fused preprocess: features (blocks 0..5951) + weights (5952..6079) ----------------
__global__ __launch_bounds__(256) void prep_all(const float* __restrict__ f,
                                                const float* __restrict__ W1,
                                                unsigned short* __restrict__ Ph,
                                                unsigned short* __restrict__ Pl,
                                                unsigned short* __restrict__ Wh,
                                                unsigned short* __restrict__ Wl) {
    int blk = blockIdx.x;
    if (blk < 5952) {
        // features -> [b][cic][lk][q][8], zeros in halo/pad
        int id = blk * 256 + threadIdx.x;
        int q = id % (int)QDIM; int r = id / (int)QDIM;
        int cic = r % 64; int b = r / 64;
        int pp = q - 53;
        int rr = pp / 52, cc = pp - rr * 52;
        int h = rr - 1, w = cc - 1;
        bool inb = (pp >= 0) && (pp < 2704) && (h >= 0) && (h < HDIM) && (w >= 0) && (w < WDIM);
        ushort8v hv0, lv0, hv1, lv1;
#pragma unroll
        for (int j = 0; j < 16; ++j) {
            float v = 0.f;
            if (inb) v = f[(((size_t)b * CIN + cic * 16 + j) * HDIM + h) * WDIM + w];
            unsigned short hi, lo;
            split2bf16(v, hi, lo);
            if (j < 8) { hv0[j] = hi; lv0[j] = lo; }
            else       { hv1[j - 8] = hi; lv1[j - 8] = lo; }
        }
        size_t b0 = ((size_t)((b * 64 + cic) * 2 + 0)) * PLSTRIDE + (size_t)q * 8;
        size_t b1 = ((size_t)((b * 64 + cic) * 2 + 1)) * PLSTRIDE + (size_t)q * 8;
        *(ushort8v*)&Ph[b0] = hv0;
        *(ushort8v*)&Ph[b1] = hv1;
        *(ushort8v*)&Pl[b0] = lv0;
        *(ushort8v*)&Pl[b1] = lv1;
    } else {
        // weights -> [cot8][cic][tap][lk][co64][8]
        int id = (blk - 5952) * 256 + threadIdx.x;
        int co = id % 64; int r = id / 64;
        int cic = r % 64; int cot = r / 64;
        int cog = cot * 64 + co;
        const float* src = W1 + ((size_t)cog * CIN + cic * 16) * 9;
        float v[144];
#pragma unroll
        for (int i = 0; i < 36; ++i) {
            float4 x = ((const float4*)src)[i];
            v[i * 4 + 0] = x.x; v[i * 4 + 1] = x.y; v[i * 4 + 2] = x.z; v[i * 4 + 3] = x.w;
        }
#pragma unroll
        for (int tap = 0; tap < 9; ++tap) {
            ushort8v hv0, lv0, hv1, lv1;
#pragma unroll
            for (int j = 0; j < 16; ++j) {
                unsigned short hi, lo;
                split2bf16(v[j * 9 + tap], hi, lo);
                if (j < 8) { hv0[j] = hi; lv0[j] = lo; }
                else       { hv1[j - 8] = hi; lv1[j - 8] = lo; }
            }
            size_t base = (((size_t)(cot * 64 + cic) * 9 + tap) * 2) * 512;
            *(ushort8v*)&Wh[base + co * 8]       = hv0;   // lk=0
            *(ushort8v*)&Wh[base + 512 + co * 8] = hv1;   // lk=1
            *(ushort8v*)&Wl[base + co * 8]       = lv0;
            *(ushort8v*)&Wl[base + 512 + co * 8] = lv1;
        }
    }
}

// ---------------- conv 3x3: flat-p' implicit GEMM, split-bf16 MFMA 32x32x16 ----------------
// v11 = v9 + B off the LDS port. Port accounting at v9: A-reads(12) + B-reads(12) per
// wave per phase = 192 b128/CU-phase x 12cy = 2304cy ~= the whole phase slot -> LDS
// read port saturated while matrix sits at 65%. B is wave-invariant within a block
// (address independent of wv), so load it global->VGPR (12 dwordx4/phase, L1-broadcast
// across the block's 4 waves). Consequences: LDS port demand halves (A only); B needs
// NO barrier (VMEM->reg); B-staging gl_lds gone; LDS = static 49,152B A-double-buffer;
// barriers 192 -> 64 (one per cic between tg1/tg2, draining the 24 A-chunks staged in
// tg0/tg1; wave skew <= 1 cic touches only disjoint buffers - audited). B loads issue
// BEFORE A-staging so vmcnt waits for B never drain in-flight A stages (in-order cnt).
// grid: 704 = b(8) x ptile(11) x cot(8). Block: 256 px (8 m-frags) x 64 co, 4 waves.

#define LOADA(SET_, SRC_, TG_)                                                       \
    do {                                                                             \
        _Pragma("unroll") for (int tl_ = 0; tl_ < 3; ++tl_) {                        \
            const int dlt_ = ((TG_) - 1) * 52 + (tl_ - 1);                           \
            _Pragma("unroll") for (int jm_ = 0; jm_ < 2; ++jm_) {                    \
                int ad_ = ((wv * 2 + jm_) * 32 + lm + dlt_ + 53) * 8;                \
                SET_[tl_][jm_][0] = *(const bf16x8*)&(SRC_)[lk * 3072 + ad_];        \
                SET_[tl_][jm_][1] = *(const bf16x8*)&(SRC_)[(2 + lk) * 3072 + ad_];  \
            }                                                                        \
        }                                                                            \
    } while (0)

#define MFMA12A(SET_, TL_, B_)                                                       \
    do {                                                                             \
        _Pragma("unroll") for (int s_ = 0; s_ < 3; ++s_)                             \
        _Pragma("unroll") for (int jm_ = 0; jm_ < 2; ++jm_)                          \
        _Pragma("unroll") for (int jn_ = 0; jn_ < 2; ++jn_) {                        \
            const bf16x8 &av_ = (s_ == 2) ? SET_[TL_][jm_][1] : SET_[TL_][jm_][0];   \
            const bf16x8 &bv_ = (s_ == 1) ? B_[jn_][1] : B_[jn_][0];                 \
            acc[jm_][jn_] = __builtin_amdgcn_mfma_f32_32x32x16_bf16(                 \
                av_, bv_, acc[jm_][jn_], 0, 0, 0);                                   \
        }                                                                            \
    } while (0)

// one phase: B(this phase) global->VGPR at top (before A staging!), compute 3 tl with
// CUR_ A-registers, prefetch NXT_ A-registers from PRESRC_ during the MFMA window.
#define PHASEV(CUR_, NXT_, CIC_, TG_, PRESRC_, NTG_, DOA_, DOLOADA_)                 \
    do {                                                                             \
        size_t wo_ = (size_t)(cot * 64 + (CIC_)) * 9216 + (size_t)((TG_) * 3072);    \
        bf16x8 bb_[3][2][2];                                                         \
        _Pragma("unroll") for (int tl_ = 0; tl_ < 3; ++tl_)                          \
        _Pragma("unroll") for (int jn_ = 0; jn_ < 2; ++jn_) {                        \
            size_t o_ = wo_ + (size_t)(tl_ * 1024 + lk * 512 + (jn_ * 32 + lm) * 8); \
            bb_[tl_][jn_][0] = *(const bf16x8*)&WPh[o_];                             \
            bb_[tl_][jn_][1] = *(const bf16x8*)&WPl[o_];                             \
        }                                                                            \
        if (DOA_) {                                                                  \
            _Pragma("unroll") for (int j_ = 0; j_ < 3; ++j_)                         \
                stageA(abn_, (CIC_) + 1, (TG_) * 12 + wv * 3 + j_);                  \
        }                                                                            \
        __builtin_amdgcn_s_setprio(1);                                               \
        MFMA12A(CUR_, 0, bb_[0]);                                                    \
        if (DOLOADA_) LOADA(NXT_, PRESRC_, NTG_);                                    \
        MFMA12A(CUR_, 1, bb_[1]);                                                    \
        MFMA12A(CUR_, 2, bb_[2]);                                                    \
        __builtin_amdgcn_s_setprio(0);                                               \
        if (DOLOADA_) {                                                              \
            /* T19 pins: [VMEM all][{3 MFMA,1 DS}x12] */                             \
            __builtin_amdgcn_sched_group_barrier(0x070, (DOA_) ? 27 : 24, 0);        \
            _Pragma("unroll") for (int g_ = 0; g_ < 12; ++g_) {                      \
                __builtin_amdgcn_sched_group_barrier(0x008, 3, 0);                   \
                __builtin_amdgcn_sched_group_barrier(0x100, 1, 0);                   \
            }                                                                        \
        }                                                                            \
    } while (0)

// one cic: tg0 computes CUR loads NXT; tg1 computes NXT loads CUR; BARRIER (drains the
// 24 A(cic+1) chunks staged in tg0/tg1); tg2 computes CUR, loads NXT from next buffer.
#define DO_CICV(CUR_, NXT_, CIC_, STAGEON_, LOADLAST_)                               \
    do {                                                                             \
        const unsigned short* bAc_ = Abase + ((CIC_) & 1) * 12288;                   \
        const unsigned short* bAn_ = Abase + (((CIC_) & 1) ^ 1) * 12288;             \
        const int abn_ = ((CIC_) & 1) ^ 1;                                           \
        PHASEV(CUR_, NXT_, CIC_, 0, bAc_, 1, STAGEON_, 1);                           \
        PHASEV(NXT_, CUR_, CIC_, 1, bAc_, 2, STAGEON_, 1);                           \
        __syncthreads();                                                             \
        PHASEV(CUR_, NXT_, CIC_, 2, bAn_, 0, 0, LOADLAST_);                          \
    } while (0)

__global__ __launch_bounds__(256, 2) void conv_mfma(const unsigned short* __restrict__ FPh,
                                                    const unsigned short* __restrict__ FPl,
                                                    const unsigned short* __restrict__ WPh,
                                                    const unsigned short* __restrict__ WPl,
                                                    const float* __restrict__ b1,
                                                    unsigned short* __restrict__ Tph,
                                                    unsigned short* __restrict__ Tpl) {
    __shared__ unsigned short sA[2][4][3072];   // [buf][hl*2+lk][384 entries x 8] = 49,152 B
    unsigned short* const Abase = &sA[0][0][0];

    int blk = blockIdx.x;
    int logical = (blk & 7) * 88 + (blk >> 3);   // XCD-aware swizzle (bijective, 704 % 8 == 0)
    int cot = logical & 7;
    int ptile = (logical >> 3) % 11;
    int b = logical / 88;
    int co0 = cot * 64;
    int P0 = 32 + ptile * 256;      // base p' of this tile; staged q range = [P0, P0+383]

    int t = threadIdx.x, wv = t >> 6, ln = t & 63;
    int lm = ln & 31, lk = ln >> 5;

    f32x16 acc[2][2];
#pragma unroll
    for (int jm = 0; jm < 2; ++jm)
#pragma unroll
        for (int jn = 0; jn < 2; ++jn)
#pragma unroll
            for (int rg = 0; rg < 16; ++rg) acc[jm][jn][rg] = 0.f;

    // A chunk ci in [0,24): region r = ci&3 (= hl*2+lk), s = ci>>2
    auto stageA = [&](int buf, int cic, int ci) {
        int r = ci & 3, s = ci >> 2;
        int hl = r >> 1, lkc = r & 1;
        const unsigned short* pl = hl ? FPl : FPh;
        const unsigned short* src = pl
            + ((size_t)((b * 64 + cic) * 2 + lkc)) * PLSTRIDE
            + (size_t)P0 * 8 + s * 512 + ln * 8;
        gl_lds(src, &Abase[buf * 12288 + r * 3072 + s * 512]);
    };

    // prologue: stage A(cic=0) fully (24 chunks, 6 per wave)
#pragma unroll
    for (int k = 0; k < 6; ++k) stageA(0, 0, wv * 6 + k);
    __syncthreads();

    bf16x8 aX[3][2][2], aY[3][2][2];
    LOADA(aX, Abase, 0);   // A(cic0, tg0) into the first compute set

#pragma unroll 1
    for (int cc = 0; cc < 31; ++cc) {
        DO_CICV(aX, aY, 2 * cc,     1, 1);
        DO_CICV(aY, aX, 2 * cc + 1, 1, 1);
    }
    DO_CICV(aX, aY, 62, 1, 1);
    DO_CICV(aY, aX, 63, 0, 0);

    // epilogue: bias+relu, split to bf16 hi/lo, store in proj-A-frag plane order
#pragma unroll
    for (int jn = 0; jn < 2; ++jn) {
        int co = co0 + jn * 32 + lm;
        float bv = b1[co];
#pragma unroll
        for (int jm = 0; jm < 2; ++jm) {
#pragma unroll
            for (int rg = 0; rg < 16; ++rg) {
                int mrow = (rg & 3) + 8 * (rg >> 2) + 4 * lk;
                int pp = P0 + (wv * 2 + jm) * 32 + mrow;
                int rr = pp / 52, cc = pp - rr * 52;
                int h = rr - 1, w = cc - 1;
                if ((unsigned)h < HDIM && (unsigned)w < WDIM) {
                    float v = fmaxf(acc[jm][jn][rg] + bv, 0.f);
                    unsigned short hi, lo;
                    split2bf16(v, hi, lo);
                    int px = b * 2500 + h * 50 + w;
                    size_t sa = (((((size_t)(px >> 7) * 16 + (co >> 5)) * 8 + ((px >> 4) & 7)) * 4
                                  + ((co >> 3) & 3)) * 16 + (px & 15)) * 8 + (co & 7);
                    Tph[sa] = hi;
                    Tpl[sa] = lo;
                }
            }
        }
    }
}

// ---------------- projection (MFMA) + decode + key build ----------------
__global__ __launch_bounds__(256) void proj_decode_mfma(const unsigned short* __restrict__ Tph,
                                                        const unsigned short* __restrict__ Tpl,
                                                        const float* __restrict__ W2,
                                                        const float* __restrict__ b2,
                                                        const float* __restrict__ W3,
                                                        const float* __restrict__ b3,
                                                        float* __restrict__ boxes,
                                                        unsigned long long* __restrict__ keys) {
    __shared__ unsigned short sTh[4096], sTl[4096];
    __shared__ unsigned short sWh[1536], sWl[1536];
    __shared__ float pout[128 * 46];

    int blk = blockIdx.x;
    int px0 = blk * 128;
    int t = threadIdx.x, wv = t >> 6, ln = t & 63;
    int lm = ln & 15, q = ln >> 4;

    f32x4 acc[2][3];
#pragma unroll
    for (int jm = 0; jm < 2; ++jm)
#pragma unroll
        for (int nf = 0; nf < 3; ++nf) acc[jm][nf] = (f32x4){0.f, 0.f, 0.f, 0.f};

#pragma unroll 1
    for (int cc16 = 0; cc16 < 16; ++cc16) {
        __syncthreads();
        size_t base = ((size_t)blk * 16 + cc16) * 4096;
        if (wv == 0) {
#pragma unroll
            for (int s = 0; s < 4; ++s) gl_lds(Tph + base + s * 512 + ln * 8, &sTh[s * 512]);
        } else if (wv == 1) {
#pragma unroll
            for (int s = 4; s < 8; ++s) gl_lds(Tph + base + s * 512 + ln * 8, &sTh[s * 512]);
        } else if (wv == 2) {
#pragma unroll
            for (int s = 0; s < 4; ++s) gl_lds(Tpl + base + s * 512 + ln * 8, &sTl[s * 512]);
        } else {
#pragma unroll
            for (int s = 4; s < 8; ++s) gl_lds(Tpl + base + s * 512 + ln * 8, &sTl[s * 512]);
        }
        int c0 = cc16 * 32;
        for (int idx = t; idx < 1536; idx += 256) {
            int o = idx >> 5, ci = idx & 31;
            float v = 0.f;
            if (o < 36) v = W2[o * 512 + c0 + ci];
            else if (o < 45) v = W3[(o - 36) * 512 + c0 + ci];
            unsigned short hi, lo;
            split2bf16(v, hi, lo);
            int ad = (((o >> 4) * 4 + (ci >> 3)) * 16 + (o & 15)) * 8 + (ci & 7);
            sWh[ad] = hi; sWl[ad] = lo;
        }
        __syncthreads();

        bf16x8 a[2][2], bb[3][2];
#pragma unroll
        for (int jm = 0; jm < 2; ++jm) {
            int mf = wv * 2 + jm;
            int ad = ((mf * 4 + q) * 16 + lm) * 8;
            a[jm][0] = *(const bf16x8*)&sTh[ad];
            a[jm][1] = *(const bf16x8*)&sTl[ad];
        }
#pragma unroll
        for (int nf = 0; nf < 3; ++nf) {
            int ad = ((nf * 4 + q) * 16 + lm) * 8;
            bb[nf][0] = *(const bf16x8*)&sWh[ad];
            bb[nf][1] = *(const bf16x8*)&sWl[ad];
        }
#pragma unroll
        for (int jm = 0; jm < 2; ++jm)
#pragma unroll
            for (int nf = 0; nf < 3; ++nf) {
                acc[jm][nf] = __builtin_amdgcn_mfma_f32_16x16x32_bf16(a[jm][0], bb[nf][0], acc[jm][nf], 0, 0, 0);
                acc[jm][nf] = __builtin_amdgcn_mfma_f32_16x16x32_bf16(a[jm][0], bb[nf][1], acc[jm][nf], 0, 0, 0);
                acc[jm][nf] = __builtin_amdgcn_mfma_f32_16x16x32_bf16(a[jm][1], bb[nf][0], acc[jm][nf], 0, 0, 0);
            }
    }
    __syncthreads();
#pragma unroll
    for (int jm = 0; jm < 2; ++jm)
#pragma unroll
        for (int nf = 0; nf < 3; ++nf) {
            int o = nf * 16 + lm;
            if (o < 45) {
                float bias = (o < 36) ? b2[o] : b3[o - 36];
#pragma unroll
                for (int rg = 0; rg < 4; ++rg) {
                    int pxl = (wv * 2 + jm) * 16 + q * 4 + rg;
                    pout[pxl * 46 + o] = acc[jm][nf][rg] + bias;
                }
            }
        }
    __syncthreads();

    const float AW[9] = {90.50966799187809f, 128.0f, 181.01933598375618f,
                         181.01933598375618f, 256.0f, 362.03867196751236f,
                         362.03867196751236f, 512.0f, 724.0773439350247f};
    const float AH[9] = {181.01933598375618f, 128.0f, 90.50966799187809f,
                         362.03867196751236f, 256.0f, 181.01933598375618f,
                         724.0773439350247f, 512.0f, 362.03867196751236f};
    const float CLIPV = 4.135166556742356f;
    const float IMG = 1600.0f;

    for (int it = t; it < 128 * 9; it += 256) {
        int pxl = it / 9, a = it - pxl * 9;
        int pxg = px0 + pxl;
        if (pxg >= 20000) continue;
        int b = pxg / 2500, rem = pxg % 2500;
        int h = rem / 50, w = rem % 50;

        float tx = pout[pxl * 46 + a * 4 + 0];
        float ty = pout[pxl * 46 + a * 4 + 1];
        float tw = pout[pxl * 46 + a * 4 + 2];
        float th = pout[pxl * 46 + a * 4 + 3];
        float lg = pout[pxl * 46 + 36 + a];

        float s = 1.0f / (1.0f + expf(-lg));

        float cx = ((float)w + 0.5f) * 32.0f;
        float cy = ((float)h + 0.5f) * 32.0f;
        float x1a = cx - 0.5f * AW[a];
        float x2a = cx + 0.5f * AW[a];
        float y1a = cy - 0.5f * AH[a];
        float y2a = cy + 0.5f * AH[a];
        float waf = x2a - x1a;
        float haf = y2a - y1a;
        float cxa = x1a + 0.5f * waf;
        float cya = y1a + 0.5f * haf;

        float twc = tw < CLIPV ? tw : CLIPV;
        float thc = th < CLIPV ? th : CLIPV;
        float pxc = tx * waf + cxa;
        float pyc = ty * haf + cya;
        float pw  = expf(twc) * waf;
        float ph  = expf(thc) * haf;

        float x1 = pxc - 0.5f * pw;
        float y1 = pyc - 0.5f * ph;
        float x2 = pxc + 0.5f * pw;
        float y2 = pyc + 0.5f * ph;
        x1 = fminf(fmaxf(x1, 0.f), IMG);
        y1 = fminf(fmaxf(y1, 0.f), IMG);
        x2 = fminf(fmaxf(x2, 0.f), IMG);
        y2 = fminf(fmaxf(y2, 0.f), IMG);

        float bw = x2 - x1, bh = y2 - y1;
        bool valid = (s >= 0.1f) && (bw > 16.0f) && (bh > 16.0f);
        float m = valid ? s : -1.0f;

        int idx = (h * WDIM + w) * NA + a;
        size_t gi = (size_t)b * NANCH + idx;
        ((float4*)boxes)[gi] = make_float4(x1, y1, x2, y2);
        unsigned int u = __float_as_uint(m);
        unsigned int k32 = (u & 0x80000000u) ? ~u : (u | 0x80000000u);
        keys[gi] = ((unsigned long long)k32 << 15) | (unsigned long long)(32767 - idx);
    }
}

// ---------------- exact stable top-2000: early-exit radix select + bitonic ----------------
// stop the radix descent as soon as the candidate set above the chosen-bin lower
// boundary fits in the 2048-slot buffer; the bitonic sort orders the superset exactly
// (keys unique via idx bits), so top-2000 is unchanged.
__global__ __launch_bounds__(1024) void select_sort_kernel(const unsigned long long* __restrict__ keys,
                                                           const float* __restrict__ boxes,
                                                           float* __restrict__ top_boxes,
                                                           float* __restrict__ top_s) {
    int b = blockIdx.x;
    int t = threadIdx.x;
    int wv = t >> 6;
    const unsigned long long* kb = keys + (size_t)b * NANCH;

    __shared__ unsigned int whist[16][256];
    __shared__ unsigned int hist[256];
    __shared__ int s_chosen, s_rnew, s_done;
    __shared__ unsigned int s_cnt;
    __shared__ unsigned long long skeys[2048];

    const int widths[6] = {8, 8, 8, 8, 8, 7};
    unsigned long long prefix = 0;
    int bitsdone = 0;
    int r = PRE_N;

    if (t == 0) s_done = 0;

    for (int p = 0; p < 6; ++p) {
        int width = widths[p];
        int bins = 1 << width;
        int shift = 47 - bitsdone - width;
        for (int i = t; i < 16 * 256; i += 1024) ((unsigned int*)whist)[i] = 0;
        __syncthreads();
        for (int i = t; i < NANCH; i += 1024) {
            unsigned long long k = kb[i];
            if ((k >> (47 - bitsdone)) == prefix)
                atomicAdd(&whist[wv][(unsigned)((k >> shift) & (unsigned long long)(bins - 1))], 1u);
        }
        __syncthreads();
        if (t < bins) {
            unsigned int s = 0;
#pragma unroll
            for (int w = 0; w < 16; ++w) s += whist[w][t];
            hist[t] = s;
        }
        __syncthreads();
        if (t == 0) {
            int acc = 0, chosen = 0, rnew = 1;
            for (int d = bins - 1; d >= 0; --d) {
                int hv = (int)hist[d];
                if (acc + hv >= r) {
                    chosen = d; rnew = r - acc;
                    // keys >= (new prefix << remaining) count = (PRE_N - r) + acc + hv
                    if ((PRE_N - r) + acc + hv <= 2048) s_done = 1;
                    break;
                }
                acc += hv;
            }
            s_chosen = chosen;
            s_rnew = rnew;
        }
        __syncthreads();
        prefix = (prefix << width) | (unsigned long long)s_chosen;
        bitsdone += width;
        r = s_rnew;
        __syncthreads();
        if (s_done) break;
    }
    unsigned long long Kst = prefix << (47 - bitsdone);

    if (t == 0) s_cnt = 0;
    __syncthreads();
    for (int i = t; i < NANCH; i += 1024) {
        unsigned long long k = kb[i];
        if (k >= Kst) {
            unsigned int p = atomicAdd(&s_cnt, 1u);
            if (p < 2048) skeys[p] = k;
        }
    }
    __syncthreads();
    unsigned int cnt = s_cnt;
    for (int i = t; i < 2048; i += 1024)
        if (i >= (int)cnt) skeys[i] = 0ull;
    for (int k = 2; k <= 2048; k <<= 1) {
        for (int j = k >> 1; j > 0; j >>= 1) {
            __syncthreads();
            for (int i = t; i < 2048; i += 1024) {
                int l = i ^ j;
                if (l > i) {
                    unsigned long long a = skeys[i], c = skeys[l];
                    bool up = ((i & k) == 0);
                    if (up ? (a < c) : (a > c)) { skeys[i] = c; skeys[l] = a; }
                }
            }
        }
    }
    __syncthreads();
    for (int i = t; i < PRE_N; i += 1024) {
        unsigned long long k = skeys[i];
        unsigned int k32 = (unsigned int)(k >> 15);
        float m = (k32 & 0x80000000u) ? __uint_as_float(k32 & 0x7FFFFFFFu)
                                      : __uint_as_float(~k32);
        unsigned int idx = 32767u - (unsigned int)(k & 32767ull);
        size_t gi = (size_t)b * NANCH + idx;
        top_s[b * PRE_N + i] = m;
        ((float4*)top_boxes)[b * PRE_N + i] = ((const float4*)boxes)[gi];
    }
}

// ---------------- IoU suppression bit-matrix ----------------
__global__ __launch_bounds__(256) void sup_kernel(const float* __restrict__ top_boxes,
                                                  unsigned long long* __restrict__ supm) {
    int blk = blockIdx.x;
    int b = blk / 125;
    int chunk = blk % 125;
    int t = threadIdx.x;

    __shared__ float bx1[PRE_N], by1[PRE_N], bx2[PRE_N], by2[PRE_N];
    for (int i = t; i < PRE_N; i += 256) {
        float4 v = ((const float4*)top_boxes)[b * PRE_N + i];
        bx1[i] = v.x; by1[i] = v.y; bx2[i] = v.z; by2[i] = v.w;
    }
    __syncthreads();

    int wave = t >> 6, lane = t & 63;
    for (int rr = 0; rr < 4; ++rr) {
        int i = chunk * 16 + wave * 4 + rr;
        float ax1 = bx1[i], ay1 = by1[i], ax2 = bx2[i], ay2 = by2[i];
        float aarea = (ax2 - ax1) * (ay2 - ay1);
        for (int jw = 0; jw < 32; ++jw) {
            int j = jw * 64 + lane;
            bool sup = false;
            if (j > i && j < PRE_N) {
                float jx1 = bx1[j], jy1 = by1[j], jx2 = bx2[j], jy2 = by2[j];
                float ix1 = fmaxf(ax1, jx1), iy1 = fmaxf(ay1, jy1);
                float ix2 = fminf(ax2, jx2), iy2 = fminf(ay2, jy2);
                float iw = fmaxf(ix2 - ix1, 0.f);
                float ih = fmaxf(iy2 - iy1, 0.f);
                float inter = iw * ih;
                float barea = (jx2 - jx1) * (jy2 - jy1);
                float iou = inter / (aarea + barea - inter + 1e-9f);
                sup = iou > 0.7f;
            }
            unsigned long long m = __ballot(sup);
            if (lane == 0) supm[((size_t)b * PRE_N + i) * 32 + jw] = m;
        }
    }
}

// ---------------- fused: tiled NMS scan (wave 0) + stable top-100 finalize ----------------
__global__ __launch_bounds__(256) void nms_fin_kernel(const float* __restrict__ top_s,
                                                      const unsigned long long* __restrict__ supm,
                                                      const float* __restrict__ top_boxes,
                                                      float* __restrict__ out) {
    int b = blockIdx.x;
    int t = threadIdx.x;
    __shared__ unsigned int kw[64];
    __shared__ int wpre[65];

    if (t < 64) {
        int lane = t;
        unsigned int alive = 0;
        for (int q = 0; q < 32; ++q) {
            int i = lane * 32 + q;
            if (i < PRE_N && top_s[b * PRE_N + i] > 0.f) alive |= (1u << q);
        }
        const unsigned long long* sm = supm + (size_t)b * PRE_N * 32;
        const unsigned int* sup32 = (const unsigned int*)sm;

        for (int tt = 0; tt < 32; ++tt) {
            unsigned int alo = __shfl(alive, 2 * tt);
            unsigned int ahi = __shfl(alive, 2 * tt + 1);
            unsigned long long talive = (unsigned long long)alo | ((unsigned long long)ahi << 32);
            int i_row = tt * 64 + lane;
            unsigned long long rm = (i_row < PRE_N) ? sm[(size_t)i_row * 32 + tt] : 0ull;

            unsigned long long kept = 0, rem = talive;
            while (rem) {
                int j = __builtin_ctzll(rem);
                kept |= (1ull << j);
                unsigned long long rmj = __shfl(rm, j);
                rem &= ~rmj;
                rem &= ~(1ull << j);
            }

            // 8-wide OR-accumulation: 8 independent loads per latency round
            unsigned int oracc = 0;
            unsigned long long kk = kept;
            while (kk) {
                int j0 = __builtin_ctzll(kk); kk &= kk - 1;
                int j1 = -1, j2 = -1, j3 = -1, j4 = -1, j5 = -1, j6 = -1, j7 = -1;
                if (kk) { j1 = __builtin_ctzll(kk); kk &= kk - 1; }
                if (kk) { j2 = __builtin_ctzll(kk); kk &= kk - 1; }
                if (kk) { j3 = __builtin_ctzll(kk); kk &= kk - 1; }
                if (kk) { j4 = __builtin_ctzll(kk); kk &= kk - 1; }
                if (kk) { j5 = __builtin_ctzll(kk); kk &= kk - 1; }
                if (kk) { j6 = __builtin_ctzll(kk); kk &= kk - 1; }
                if (kk) { j7 = __builtin_ctzll(kk); kk &= kk - 1; }
                unsigned int v0 = sup32[(size_t)(tt * 64 + j0) * 64 + lane];
                unsigned int v1 = (j1 >= 0) ? sup32[(size_t)(tt * 64 + j1) * 64 + lane] : 0u;
                unsigned int v2 = (j2 >= 0) ? sup32[(size_t)(tt * 64 + j2) * 64 + lane] : 0u;
                unsigned int v3 = (j3 >= 0) ? sup32[(size_t)(tt * 64 + j3) * 64 + lane] : 0u;
                unsigned int v4 = (j4 >= 0) ? sup32[(size_t)(tt * 64 + j4) * 64 + lane] : 0u;
                unsigned int v5 = (j5 >= 0) ? sup32[(size_t)(tt * 64 + j5) * 64 + lane] : 0u;
                unsigned int v6 = (j6 >= 0) ? sup32[(size_t)(tt * 64 + j6) * 64 + lane] : 0u;
                unsigned int v7 = (j7 >= 0) ? sup32[(size_t)(tt * 64 + j7) * 64 + lane] : 0u;
                oracc |= (v0 | v1) | (v2 | v3) | (v4 | v5) | (v6 | v7);
            }
            alive &= ~oracc;
            if (lane == 2 * tt)     alive = (unsigned int)kept;
            if (lane == 2 * tt + 1) alive = (unsigned int)(kept >> 32);
        }
        kw[lane] = alive;
    }
    __syncthreads();
    if (t == 0) {
        int run = 0;
        for (int w = 0; w < 64; ++w) { wpre[w] = run; run += __popc(kw[w]); }
        wpre[64] = run;
    }
    __syncthreads();
    int total = wpre[64];
    float* out_boxes  = out;
    float* out_scores = out + NB * POST_N * 4;
    for (int i = t; i < PRE_N; i += 256) {
        unsigned int w = kw[i >> 5];
        bool kept = (w >> (i & 31)) & 1u;
        int rk = wpre[i >> 5] + __popc(w & ((1u << (i & 31)) - 1u));
        int pos = kept ? rk : total + (i - rk);
        if (pos < POST_N) {
            out_scores[b * POST_N + pos] = kept ? top_s[b * PRE_N + i] : -1.0f;
            ((float4*)out_boxes)[b * POST_N + pos] = ((const float4*)top_boxes)[b * PRE_N + i];
        }
    }
}

// ---------------- launch ----------------
extern "C" void kernel_launch(void* const* d_in, const int* in_sizes, int n_in,
                              void* d_out, int out_size, void* d_ws, size_t ws_size,
                              hipStream_t stream) {
    const float* features = (const float*)d_in[0];
    const float* W1 = (const float*)d_in[1];
    const float* b1 = (const float*)d_in[2];
    const float* W2 = (const float*)d_in[3];
    const float* b2 = (const float*)d_in[4];
    const float* W3 = (const float*)d_in[5];
    const float* b3 = (const float*)d_in[6];
    float* out = (float*)d_out;
    char* ws = (char*)d_ws;

    unsigned short* Tph = (unsigned short*)(ws + OFF_TPH);
    unsigned short* Tpl = (unsigned short*)(ws + OFF_TPL);
    float* boxes   = (float*)(ws + OFF_BOXES);
    unsigned long long* keys = (unsigned long long*)(ws + OFF_KEYS);
    float* top_boxes = (float*)(ws + OFF_TBOX);
    float* top_s     = (float*)(ws + OFF_TS);
    unsigned long long* supm = (unsigned long long*)(ws + OFF_SUP);
    unsigned short* FPh = (unsigned short*)(ws + OFF_PH);
    unsigned short* FPl = (unsigned short*)(ws + OFF_PL);
    unsigned short* WPh = (unsigned short*)(ws + OFF_WH);
    unsigned short* WPl = (unsigned short*)(ws + OFF_WL);

    prep_all<<<6080, 256, 0, stream>>>(features, W1, FPh, FPl, WPh, WPl);
    conv_mfma<<<704, 256, 0, stream>>>(FPh, FPl, WPh, WPl, b1, Tph, Tpl);
    proj_decode_mfma<<<157, 256, 0, stream>>>(Tph, Tpl, W2, b2, W3, b3, boxes, keys);
    select_sort_kernel<<<NB, 1024, 0, stream>>>(keys, boxes, top_boxes, top_s);
    sup_kernel<<<NB * 125, 256, 0, stream>>>(top_boxes, supm);
    nms_fin_kernel<<<NB, 256, 0, stream>>>(top_s, supm, top_boxes, out);
}

// Round 12
// 936.247 us; speedup vs baseline: 1.1352x; 1.1352x over previous
//
#include <hip/hip_runtime.h>
#include <cstdint>

#define NB 8
#define CIN 1024
#define HDIM 50
#define WDIM 50
#define COUT 512
#define NA 9
#define NANCH (HDIM*WDIM*NA)   /* 22500 */
#define PRE_N 2000
#define POST_N 100

typedef __attribute__((ext_vector_type(8))) short bf16x8;
typedef __attribute__((ext_vector_type(4))) float f32x4;
typedef __attribute__((ext_vector_type(16))) float f32x16;
typedef __attribute__((ext_vector_type(8))) unsigned short ushort8v;

// ---------------- workspace layout (bytes) ----------------
// t planes (bf16 hi/lo) in proj-A-frag order: [pxblk157][cchunk16][mf8][q4][pxl16][j8]
constexpr size_t TPLANE    = 20578304;                   // 157*16*4096 shorts * 2B
constexpr size_t OFF_TPH   = 0;
constexpr size_t OFF_TPL   = 20578304;
constexpr size_t OFF_BOXES = 41156608;                   // 8*22500*4 f32
constexpr size_t OFF_KEYS  = 44036608;                   // 8*22500 u64
constexpr size_t OFF_TBOX  = 45476608;                   // 8*2000*4 f32
constexpr size_t OFF_TS    = 45732608;                   // 8*2000 f32
constexpr size_t OFF_SUP   = 45796608;                   // 8*2000*32 u64 (4.1MB)
// W2/W3 split planes live in the first 98KB of OFF_SUP: written by prep_all, read by
// proj_decode, then overwritten by sup_kernel (which runs strictly after proj).
constexpr size_t OFF_W23H  = OFF_SUP;                    // 16*1536 shorts = 49,152 B
constexpr size_t OFF_W23L  = OFF_SUP + 49152;
// feature planes, flat-padded-pixel layout: [b8][cic64][lk2][q2976][ci8] bf16
//   q = p' + 53, p' = rr*52+cc on the 52x52 zero-padded grid (rr,cc in 0..51)
constexpr size_t QDIM      = 2976;                       // covers q up to 2975 (stage max 2975)
constexpr size_t PLSTRIDE  = QDIM * 8;                   // shorts per (b,cic,lk) = 23808
constexpr size_t PPLANE    = 48758784;                   // 8*64*2*23808*2B
constexpr size_t OFF_PH    = 49892864;
constexpr size_t OFF_PL    = OFF_PH + PPLANE;            // 98,651,648
// weight planes: [cot8][cic64][tap9][lk2][co64][ci8] bf16
constexpr size_t WPLANE    = 9437184;
constexpr size_t OFF_WH    = 147410432;
constexpr size_t OFF_WL    = OFF_WH + WPLANE;            // end ~166.3 MB

__device__ __forceinline__ void split2bf16(float v, unsigned short &hi, unsigned short &lo) {
    unsigned int u = __float_as_uint(v);
    unsigned int r = u + 0x7FFFu + ((u >> 16) & 1u);
    hi = (unsigned short)(r >> 16);
    float hf = __uint_as_float(((unsigned int)hi) << 16);
    float lf = v - hf;
    unsigned int u2 = __float_as_uint(lf);
    unsigned int r2 = u2 + 0x7FFFu + ((u2 >> 16) & 1u);
    lo = (unsigned short)(r2 >> 16);
}

__device__ __forceinline__ void gl_lds(const unsigned short* g, unsigned short* l) {
    __builtin_amdgcn_global_load_lds(
        (const __attribute__((address_space(1))) unsigned int*)(const void*)g,
        (__attribute__((address_space(3))) unsigned int*)(void*)l,
        16, 0, 0);
}

// ---------------- fused preprocess: features (0..5951) + W1 (5952..6079) + W2/W3 (6080..6087) ----------------
__global__ __launch_bounds__(256) void prep_all(const float* __restrict__ f,
                                                const float* __restrict__ W1,
                                                const float* __restrict__ W2,
                                                const float* __restrict__ W3,
                                                unsigned short* __restrict__ Ph,
                                                unsigned short* __restrict__ Pl,
                                                unsigned short* __restrict__ Wh,
                                                unsigned short* __restrict__ Wl,
                                                unsigned short* __restrict__ W23h,
                                                unsigned short* __restrict__ W23l) {
    int blk = blockIdx.x;
    if (blk < 5952) {
        // features -> [b][cic][lk][q][8], zeros in halo/pad
        int id = blk * 256 + threadIdx.x;
        int q = id % (int)QDIM; int r = id / (int)QDIM;
        int cic = r % 64; int b = r / 64;
        int pp = q - 53;
        int rr = pp / 52, cc = pp - rr * 52;
        int h = rr - 1, w = cc - 1;
        bool inb = (pp >= 0) && (pp < 2704) && (h >= 0) && (h < HDIM) && (w >= 0) && (w < WDIM);
        ushort8v hv0, lv0, hv1, lv1;
#pragma unroll
        for (int j = 0; j < 16; ++j) {
            float v = 0.f;
            if (inb) v = f[(((size_t)b * CIN + cic * 16 + j) * HDIM + h) * WDIM + w];
            unsigned short hi, lo;
            split2bf16(v, hi, lo);
            if (j < 8) { hv0[j] = hi; lv0[j] = lo; }
            else       { hv1[j - 8] = hi; lv1[j - 8] = lo; }
        }
        size_t b0 = ((size_t)((b * 64 + cic) * 2 + 0)) * PLSTRIDE + (size_t)q * 8;
        size_t b1 = ((size_t)((b * 64 + cic) * 2 + 1)) * PLSTRIDE + (size_t)q * 8;
        *(ushort8v*)&Ph[b0] = hv0;
        *(ushort8v*)&Ph[b1] = hv1;
        *(ushort8v*)&Pl[b0] = lv0;
        *(ushort8v*)&Pl[b1] = lv1;
    } else if (blk < 6080) {
        // weights -> [cot8][cic][tap][lk][co64][8]
        int id = (blk - 5952) * 256 + threadIdx.x;
        int co = id % 64; int r = id / 64;
        int cic = r % 64; int cot = r / 64;
        int cog = cot * 64 + co;
        const float* src = W1 + ((size_t)cog * CIN + cic * 16) * 9;
        float v[144];
#pragma unroll
        for (int i = 0; i < 36; ++i) {
            float4 x = ((const float4*)src)[i];
            v[i * 4 + 0] = x.x; v[i * 4 + 1] = x.y; v[i * 4 + 2] = x.z; v[i * 4 + 3] = x.w;
        }
#pragma unroll
        for (int tap = 0; tap < 9; ++tap) {
            ushort8v hv0, lv0, hv1, lv1;
#pragma unroll
            for (int j = 0; j < 16; ++j) {
                unsigned short hi, lo;
                split2bf16(v[j * 9 + tap], hi, lo);
                if (j < 8) { hv0[j] = hi; lv0[j] = lo; }
                else       { hv1[j - 8] = hi; lv1[j - 8] = lo; }
            }
            size_t base = (((size_t)(cot * 64 + cic) * 9 + tap) * 2) * 512;
            *(ushort8v*)&Wh[base + co * 8]       = hv0;   // lk=0
            *(ushort8v*)&Wh[base + 512 + co * 8] = hv1;   // lk=1
            *(ushort8v*)&Wl[base + co * 8]       = lv0;
            *(ushort8v*)&Wl[base + 512 + co * 8] = lv1;
        }
    } else {
        // W2/W3 -> proj-frag planes: [cc16][ (((o>>4)*4+(ci>>3))*16+(o&15))*8+(ci&7) ]
        // o in [0,48), o>=45 zeroed (matches proj's original in-kernel staging).
        int id = (blk - 6080) * 256 + threadIdx.x;   // 0..2047
        for (int e = id; e < 48 * 512; e += 8 * 256) {
            int o = e >> 9, c = e & 511;
            float v = 0.f;
            if (o < 36) v = W2[o * 512 + c];
            else if (o < 45) v = W3[(o - 36) * 512 + c];
            unsigned short hi, lo;
            split2bf16(v, hi, lo);
            int cc16 = c >> 5, ci = c & 31;
            int ad = cc16 * 1536 + (((o >> 4) * 4 + (ci >> 3)) * 16 + (o & 15)) * 8 + (ci & 7);
            W23h[ad] = hi;
            W23l[ad] = lo;
        }
    }
}

// ---------------- conv 3x3: flat-p' implicit GEMM, split-bf16 MFMA 32x32x16 ----------------
// v12 conv = v9/v10 verbatim (measured 495us, MfmaUtil 65). v11's B->VGPR attempt
// spilled (VGPR report 128 + WRITE_SIZE +21MB scratch) and regressed to 632 — both
// neighbors of this schedule (more LDS traffic, more VGPR pressure) lose; this is the
// local structural optimum for the family.
// grid: 704 = b(8) x ptile(11) x cot(8). Block: 256 px (8 m-frags) x 64 co, 4 waves.

#define LOADA(SET_, SRC_, TG_)                                                       \
    do {                                                                             \
        _Pragma("unroll") for (int tl_ = 0; tl_ < 3; ++tl_) {                        \
            const int dlt_ = ((TG_) - 1) * 52 + (tl_ - 1);                           \
            _Pragma("unroll") for (int jm_ = 0; jm_ < 2; ++jm_) {                    \
                int ad_ = ((wv * 2 + jm_) * 32 + lm + dlt_ + 53) * 8;                \
                SET_[tl_][jm_][0] = *(const bf16x8*)&(SRC_)[lk * 3072 + ad_];        \
                SET_[tl_][jm_][1] = *(const bf16x8*)&(SRC_)[(2 + lk) * 3072 + ad_];  \
            }                                                                        \
        }                                                                            \
    } while (0)

#define LOADB(B_, BB_, TL_)                                                          \
    do {                                                                             \
        _Pragma("unroll") for (int jn_ = 0; jn_ < 2; ++jn_) {                        \
            int bd_ = (TL_) * 1024 + lk * 512 + (jn_ * 32 + lm) * 8;                 \
            B_[jn_][0] = *(const bf16x8*)&(BB_)[bd_];                                \
            B_[jn_][1] = *(const bf16x8*)&(BB_)[3072 + bd_];                         \
        }                                                                            \
    } while (0)

#define MFMA12A(SET_, TL_, B_)                                                       \
    do {                                                                             \
        _Pragma("unroll") for (int s_ = 0; s_ < 3; ++s_)                             \
        _Pragma("unroll") for (int jm_ = 0; jm_ < 2; ++jm_)                          \
        _Pragma("unroll") for (int jn_ = 0; jn_ < 2; ++jn_) {                        \
            const bf16x8 &av_ = (s_ == 2) ? SET_[TL_][jm_][1] : SET_[TL_][jm_][0];   \
            const bf16x8 &bv_ = (s_ == 1) ? B_[jn_][1] : B_[jn_][0];                 \
            acc[jm_][jn_] = __builtin_amdgcn_mfma_f32_32x32x16_bf16(                 \
                av_, bv_, acc[jm_][jn_], 0, 0, 0);                                   \
        }                                                                            \
    } while (0)

// one phase: compute with CUR_ (preloaded A) + B from LDS; prefetch NXT_ from PRESRC_.
#define PHASE(CUR_, NXT_, CIC_, TG_, PRESRC_, NTG_, STAGEON_)                        \
    do {                                                                             \
        const int bbuf_ = ((CIC_) + (TG_)) & 1;                                      \
        const unsigned short* bB_ = Bbase + bbuf_ * 6144;                            \
        if ((STAGEON_) || (TG_) < 2) {                                               \
            int cicb_ = ((TG_) == 2) ? (CIC_) + 1 : (CIC_);                          \
            int tgn_  = ((TG_) == 2) ? 0 : (TG_) + 1;                                \
            _Pragma("unroll") for (int j_ = 0; j_ < 3; ++j_)                         \
                stageB(bbuf_ ^ 1, cicb_, tgn_, wv * 3 + j_);                         \
        }                                                                            \
        if (STAGEON_) {                                                              \
            if ((TG_) == 0) {                                                        \
                _Pragma("unroll") for (int j_ = 0; j_ < 3; ++j_)                     \
                    stageA((((CIC_) & 1) ^ 1), (CIC_) + 1, wv * 3 + j_);             \
            } else if ((TG_) == 1) {                                                 \
                _Pragma("unroll") for (int j_ = 0; j_ < 2; ++j_)                     \
                    stageA((((CIC_) & 1) ^ 1), (CIC_) + 1, 12 + wv * 2 + j_);        \
            } else {                                                                 \
                stageA((((CIC_) & 1) ^ 1), (CIC_) + 1, 20 + wv);                     \
            }                                                                        \
        }                                                                            \
        bf16x8 b0_[2][2], b1_[2][2];                                                 \
        LOADB(b0_, bB_, 0);                                                          \
        __builtin_amdgcn_s_setprio(1);                                               \
        LOADB(b1_, bB_, 1);                                                          \
        MFMA12A(CUR_, 0, b0_);                                                       \
        LOADB(b0_, bB_, 2);                                                          \
        if ((STAGEON_) || (TG_) < 2) LOADA(NXT_, PRESRC_, NTG_);                     \
        MFMA12A(CUR_, 1, b1_);                                                       \
        MFMA12A(CUR_, 2, b0_);                                                       \
        __builtin_amdgcn_s_setprio(0);                                               \
        if (STAGEON_) {                                                              \
            const int nv_ = ((TG_) == 0) ? 6 : ((TG_) == 1) ? 5 : 4;                 \
            __builtin_amdgcn_sched_group_barrier(0x070, nv_, 0);                     \
            __builtin_amdgcn_sched_group_barrier(0x100, 8, 0);                       \
            _Pragma("unroll") for (int g_ = 0; g_ < 8; ++g_) {                       \
                __builtin_amdgcn_sched_group_barrier(0x008, 3, 0);                   \
                __builtin_amdgcn_sched_group_barrier(0x100, 2, 0);                   \
            }                                                                        \
            __builtin_amdgcn_sched_group_barrier(0x008, 12, 0);                      \
        }                                                                            \
        __syncthreads();                                                             \
    } while (0)

// set rotation within a cic: tg0 computes CUR loads NXT; tg1 computes NXT loads CUR;
// tg2 computes CUR loads NXT (next-cic tg0 from the other A buffer).
#define DO_CIC(CUR_, NXT_, CIC_, STAGEON_)                                           \
    do {                                                                             \
        const unsigned short* bAc_ = Abase + ((CIC_) & 1) * 12288;                   \
        const unsigned short* bAn_ = Abase + (((CIC_) & 1) ^ 1) * 12288;             \
        PHASE(CUR_, NXT_, CIC_, 0, bAc_, 1, STAGEON_);                               \
        PHASE(NXT_, CUR_, CIC_, 1, bAc_, 2, STAGEON_);                               \
        PHASE(CUR_, NXT_, CIC_, 2, bAn_, 0, STAGEON_);                               \
    } while (0)

__global__ __launch_bounds__(256, 2) void conv_mfma(const unsigned short* __restrict__ FPh,
                                                    const unsigned short* __restrict__ FPl,
                                                    const unsigned short* __restrict__ WPh,
                                                    const unsigned short* __restrict__ WPl,
                                                    const float* __restrict__ b1,
                                                    unsigned short* __restrict__ Tph,
                                                    unsigned short* __restrict__ Tpl) {
    // LDS: A[2 buf][region4][384 x 8] = 2*12288 shorts, B[2 buf][hl2][6*512] = 2*6144 shorts
    extern __shared__ unsigned short smem[];   // 36864 shorts = 73728 B
    unsigned short* const Abase = smem;            // +0
    unsigned short* const Bbase = smem + 24576;    // A occupies 24576 shorts

    int blk = blockIdx.x;
    int logical = (blk & 7) * 88 + (blk >> 3);   // XCD-aware swizzle (bijective, 704 % 8 == 0)
    int cot = logical & 7;
    int ptile = (logical >> 3) % 11;
    int b = logical / 88;
    int co0 = cot * 64;
    int P0 = 32 + ptile * 256;      // base p' of this tile; staged q range = [P0, P0+383]

    int t = threadIdx.x, wv = t >> 6, ln = t & 63;
    int lm = ln & 31, lk = ln >> 5;

    f32x16 acc[2][2];
#pragma unroll
    for (int jm = 0; jm < 2; ++jm)
#pragma unroll
        for (int jn = 0; jn < 2; ++jn)
#pragma unroll
            for (int rg = 0; rg < 16; ++rg) acc[jm][jn][rg] = 0.f;

    // A chunk ci in [0,24): s-major so s0..s4 land in phases tg0/tg1 (20 chunks) and
    // s5 in tg2 (4 chunks). ci<20: region r=ci&3, s=ci>>2; ci>=20: r=ci-20, s=5.
    // region r = hl*2 + lkc.
    auto stageA = [&](int buf, int cic, int ci) {
        int r = (ci < 20) ? (ci & 3) : (ci - 20);
        int s = (ci < 20) ? (ci >> 2) : 5;
        int hl = r >> 1, lkc = r & 1;
        const unsigned short* pl = hl ? FPl : FPh;
        const unsigned short* src = pl
            + ((size_t)((b * 64 + cic) * 2 + lkc)) * PLSTRIDE
            + (size_t)P0 * 8 + s * 512 + ln * 8;
        gl_lds(src, &Abase[buf * 12288 + r * 3072 + s * 512]);
    };
    // B chunk c in [0,12): hl = c/6, j = c%6; tap-group tg covers taps tg*3..tg*3+2
    auto stageB = [&](int buf, int cic, int tg, int c) {
        int hl = c / 6, j = c % 6;
        const unsigned short* pl = hl ? WPl : WPh;
        const unsigned short* src = pl + (size_t)(cot * 64 + cic) * 9216
            + (size_t)(tg * 6 + j) * 512 + ln * 8;
        gl_lds(src, &Bbase[buf * 6144 + hl * 3072 + j * 512]);
    };

    // prologue: A(cic=0) -> Abuf0 (24 chunks) + B(cic=0,tg=0) -> Bbuf0 (12 chunks)
#pragma unroll
    for (int k = 0; k < 9; ++k) {
        int id = wv * 9 + k;
        if (id < 24) stageA(0, 0, id);
        else         stageB(0, 0, 0, id - 24);
    }
    __syncthreads();

    bf16x8 aX[3][2][2], aY[3][2][2];
    LOADA(aX, Abase, 0);   // A(cic0, tg0) into the first compute set

#pragma unroll 1
    for (int cc = 0; cc < 31; ++cc) {
        DO_CIC(aX, aY, 2 * cc,     1);
        DO_CIC(aY, aX, 2 * cc + 1, 1);
    }
    DO_CIC(aX, aY, 62, 1);
    DO_CIC(aY, aX, 63, 0);

    // epilogue: bias+relu, split to bf16 hi/lo, store in proj-A-frag plane order
#pragma unroll
    for (int jn = 0; jn < 2; ++jn) {
        int co = co0 + jn * 32 + lm;
        float bv = b1[co];
#pragma unroll
        for (int jm = 0; jm < 2; ++jm) {
#pragma unroll
            for (int rg = 0; rg < 16; ++rg) {
                int mrow = (rg & 3) + 8 * (rg >> 2) + 4 * lk;
                int pp = P0 + (wv * 2 + jm) * 32 + mrow;
                int rr = pp / 52, cc = pp - rr * 52;
                int h = rr - 1, w = cc - 1;
                if ((unsigned)h < HDIM && (unsigned)w < WDIM) {
                    float v = fmaxf(acc[jm][jn][rg] + bv, 0.f);
                    unsigned short hi, lo;
                    split2bf16(v, hi, lo);
                    int px = b * 2500 + h * 50 + w;
                    size_t sa = (((((size_t)(px >> 7) * 16 + (co >> 5)) * 8 + ((px >> 4) & 7)) * 4
                                  + ((co >> 3) & 3)) * 16 + (px & 15)) * 8 + (co & 7);
                    Tph[sa] = hi;
                    Tpl[sa] = lo;
                }
            }
        }
    }
}

// ---------------- projection (MFMA) + decode + key build ----------------
// v12: W2/W3 bf16 planes precomputed by prep_all (dead-region stash) and staged via
// gl_lds — removes the per-iteration 1536-elem split2bf16 + scalar LDS store loop.
__global__ __launch_bounds__(256) void proj_decode_mfma(const unsigned short* __restrict__ Tph,
                                                        const unsigned short* __restrict__ Tpl,
                                                        const unsigned short* __restrict__ W23h,
                                                        const unsigned short* __restrict__ W23l,
                                                        const float* __restrict__ b2,
                                                        const float* __restrict__ b3,
                                                        float* __restrict__ boxes,
                                                        unsigned long long* __restrict__ keys) {
    __shared__ unsigned short sTh[4096], sTl[4096];
    __shared__ unsigned short sWh[1536], sWl[1536];
    __shared__ float pout[128 * 46];

    int blk = blockIdx.x;
    int px0 = blk * 128;
    int t = threadIdx.x, wv = t >> 6, ln = t & 63;
    int lm = ln & 15, q = ln >> 4;

    f32x4 acc[2][3];
#pragma unroll
    for (int jm = 0; jm < 2; ++jm)
#pragma unroll
        for (int nf = 0; nf < 3; ++nf) acc[jm][nf] = (f32x4){0.f, 0.f, 0.f, 0.f};

#pragma unroll 1
    for (int cc16 = 0; cc16 < 16; ++cc16) {
        __syncthreads();
        size_t base = ((size_t)blk * 16 + cc16) * 4096;
        if (wv == 0) {
#pragma unroll
            for (int s = 0; s < 4; ++s) gl_lds(Tph + base + s * 512 + ln * 8, &sTh[s * 512]);
#pragma unroll
            for (int s = 0; s < 3; ++s) gl_lds(W23h + cc16 * 1536 + s * 512 + ln * 8, &sWh[s * 512]);
        } else if (wv == 1) {
#pragma unroll
            for (int s = 4; s < 8; ++s) gl_lds(Tph + base + s * 512 + ln * 8, &sTh[s * 512]);
        } else if (wv == 2) {
#pragma unroll
            for (int s = 0; s < 4; ++s) gl_lds(Tpl + base + s * 512 + ln * 8, &sTl[s * 512]);
#pragma unroll
            for (int s = 0; s < 3; ++s) gl_lds(W23l + cc16 * 1536 + s * 512 + ln * 8, &sWl[s * 512]);
        } else {
#pragma unroll
            for (int s = 4; s < 8; ++s) gl_lds(Tpl + base + s * 512 + ln * 8, &sTl[s * 512]);
        }
        __syncthreads();

        bf16x8 a[2][2], bb[3][2];
#pragma unroll
        for (int jm = 0; jm < 2; ++jm) {
            int mf = wv * 2 + jm;
            int ad = ((mf * 4 + q) * 16 + lm) * 8;
            a[jm][0] = *(const bf16x8*)&sTh[ad];
            a[jm][1] = *(const bf16x8*)&sTl[ad];
        }
#pragma unroll
        for (int nf = 0; nf < 3; ++nf) {
            int ad = ((nf * 4 + q) * 16 + lm) * 8;
            bb[nf][0] = *(const bf16x8*)&sWh[ad];
            bb[nf][1] = *(const bf16x8*)&sWl[ad];
        }
#pragma unroll
        for (int jm = 0; jm < 2; ++jm)
#pragma unroll
            for (int nf = 0; nf < 3; ++nf) {
                acc[jm][nf] = __builtin_amdgcn_mfma_f32_16x16x32_bf16(a[jm][0], bb[nf][0], acc[jm][nf], 0, 0, 0);
                acc[jm][nf] = __builtin_amdgcn_mfma_f32_16x16x32_bf16(a[jm][0], bb[nf][1], acc[jm][nf], 0, 0, 0);
                acc[jm][nf] = __builtin_amdgcn_mfma_f32_16x16x32_bf16(a[jm][1], bb[nf][0], acc[jm][nf], 0, 0, 0);
            }
    }
    __syncthreads();
#pragma unroll
    for (int jm = 0; jm < 2; ++jm)
#pragma unroll
        for (int nf = 0; nf < 3; ++nf) {
            int o = nf * 16 + lm;
            if (o < 45) {
                float bias = (o < 36) ? b2[o] : b3[o - 36];
#pragma unroll
                for (int rg = 0; rg < 4; ++rg) {
                    int pxl = (wv * 2 + jm) * 16 + q * 4 + rg;
                    pout[pxl * 46 + o] = acc[jm][nf][rg] + bias;
                }
            }
        }
    __syncthreads();

    const float AW[9] = {90.50966799187809f, 128.0f, 181.01933598375618f,
                         181.01933598375618f, 256.0f, 362.03867196751236f,
                         362.03867196751236f, 512.0f, 724.0773439350247f};
    const float AH[9] = {181.01933598375618f, 128.0f, 90.50966799187809f,
                         362.03867196751236f, 256.0f, 181.01933598375618f,
                         724.0773439350247f, 512.0f, 362.03867196751236f};
    const float CLIPV = 4.135166556742356f;
    const float IMG = 1600.0f;

    for (int it = t; it < 128 * 9; it += 256) {
        int pxl = it / 9, a = it - pxl * 9;
        int pxg = px0 + pxl;
        if (pxg >= 20000) continue;
        int b = pxg / 2500, rem = pxg % 2500;
        int h = rem / 50, w = rem % 50;

        float tx = pout[pxl * 46 + a * 4 + 0];
        float ty = pout[pxl * 46 + a * 4 + 1];
        float tw = pout[pxl * 46 + a * 4 + 2];
        float th = pout[pxl * 46 + a * 4 + 3];
        float lg = pout[pxl * 46 + 36 + a];

        float s = 1.0f / (1.0f + expf(-lg));

        float cx = ((float)w + 0.5f) * 32.0f;
        float cy = ((float)h + 0.5f) * 32.0f;
        float x1a = cx - 0.5f * AW[a];
        float x2a = cx + 0.5f * AW[a];
        float y1a = cy - 0.5f * AH[a];
        float y2a = cy + 0.5f * AH[a];
        float waf = x2a - x1a;
        float haf = y2a - y1a;
        float cxa = x1a + 0.5f * waf;
        float cya = y1a + 0.5f * haf;

        float twc = tw < CLIPV ? tw : CLIPV;
        float thc = th < CLIPV ? th : CLIPV;
        float pxc = tx * waf + cxa;
        float pyc = ty * haf + cya;
        float pw  = expf(twc) * waf;
        float ph  = expf(thc) * haf;

        float x1 = pxc - 0.5f * pw;
        float y1 = pyc - 0.5f * ph;
        float x2 = pxc + 0.5f * pw;
        float y2 = pyc + 0.5f * ph;
        x1 = fminf(fmaxf(x1, 0.f), IMG);
        y1 = fminf(fmaxf(y1, 0.f), IMG);
        x2 = fminf(fmaxf(x2, 0.f), IMG);
        y2 = fminf(fmaxf(y2, 0.f), IMG);

        float bw = x2 - x1, bh = y2 - y1;
        bool valid = (s >= 0.1f) && (bw > 16.0f) && (bh > 16.0f);
        float m = valid ? s : -1.0f;

        int idx = (h * WDIM + w) * NA + a;
        size_t gi = (size_t)b * NANCH + idx;
        ((float4*)boxes)[gi] = make_float4(x1, y1, x2, y2);
        unsigned int u = __float_as_uint(m);
        unsigned int k32 = (u & 0x80000000u) ? ~u : (u | 0x80000000u);
        keys[gi] = ((unsigned long long)k32 << 15) | (unsigned long long)(32767 - idx);
    }
}

// ---------------- exact stable top-2000: early-exit radix select + bitonic ----------------
// v12: 4-wide ILP on the key scans (8 blocks resident -> latency-bound; 4 independent
// loads per round cut exposed L2 latency ~4x). Early-exit as v8/v10.
__global__ __launch_bounds__(1024) void select_sort_kernel(const unsigned long long* __restrict__ keys,
                                                           const float* __restrict__ boxes,
                                                           float* __restrict__ top_boxes,
                                                           float* __restrict__ top_s) {
    int b = blockIdx.x;
    int t = threadIdx.x;
    int wv = t >> 6;
    const unsigned long long* kb = keys + (size_t)b * NANCH;

    __shared__ unsigned int whist[16][256];
    __shared__ unsigned int hist[256];
    __shared__ int s_chosen, s_rnew, s_done;
    __shared__ unsigned int s_cnt;
    __shared__ unsigned long long skeys[2048];

    const int widths[6] = {8, 8, 8, 8, 8, 7};
    unsigned long long prefix = 0;
    int bitsdone = 0;
    int r = PRE_N;

    if (t == 0) s_done = 0;

    for (int p = 0; p < 6; ++p) {
        int width = widths[p];
        int bins = 1 << width;
        int shift = 47 - bitsdone - width;
        for (int i = t; i < 16 * 256; i += 1024) ((unsigned int*)whist)[i] = 0;
        __syncthreads();
        int sh = 47 - bitsdone;
        for (int i0 = t; i0 < NANCH; i0 += 4096) {
            int i1 = i0 + 1024, i2 = i0 + 2048, i3 = i0 + 3072;
            unsigned long long k0 = kb[i0];
            unsigned long long k1 = kb[i1 < NANCH ? i1 : 0];
            unsigned long long k2 = kb[i2 < NANCH ? i2 : 0];
            unsigned long long k3 = kb[i3 < NANCH ? i3 : 0];
            if ((k0 >> sh) == prefix)
                atomicAdd(&whist[wv][(unsigned)((k0 >> shift) & (unsigned long long)(bins - 1))], 1u);
            if (i1 < NANCH && (k1 >> sh) == prefix)
                atomicAdd(&whist[wv][(unsigned)((k1 >> shift) & (unsigned long long)(bins - 1))], 1u);
            if (i2 < NANCH && (k2 >> sh) == prefix)
                atomicAdd(&whist[wv][(unsigned)((k2 >> shift) & (unsigned long long)(bins - 1))], 1u);
            if (i3 < NANCH && (k3 >> sh) == prefix)
                atomicAdd(&whist[wv][(unsigned)((k3 >> shift) & (unsigned long long)(bins - 1))], 1u);
        }
        __syncthreads();
        if (t < bins) {
            unsigned int s = 0;
#pragma unroll
            for (int w = 0; w < 16; ++w) s += whist[w][t];
            hist[t] = s;
        }
        __syncthreads();
        if (t == 0) {
            int acc = 0, chosen = 0, rnew = 1;
            for (int d = bins - 1; d >= 0; --d) {
                int hv = (int)hist[d];
                if (acc + hv >= r) {
                    chosen = d; rnew = r - acc;
                    // keys >= (new prefix << remaining) count = (PRE_N - r) + acc + hv
                    if ((PRE_N - r) + acc + hv <= 2048) s_done = 1;
                    break;
                }
                acc += hv;
            }
            s_chosen = chosen;
            s_rnew = rnew;
        }
        __syncthreads();
        prefix = (prefix << width) | (unsigned long long)s_chosen;
        bitsdone += width;
        r = s_rnew;
        __syncthreads();
        if (s_done) break;
    }
    unsigned long long Kst = prefix << (47 - bitsdone);

    if (t == 0) s_cnt = 0;
    __syncthreads();
    for (int i0 = t; i0 < NANCH; i0 += 4096) {
        int i1 = i0 + 1024, i2 = i0 + 2048, i3 = i0 + 3072;
        unsigned long long k0 = kb[i0];
        unsigned long long k1 = kb[i1 < NANCH ? i1 : 0];
        unsigned long long k2 = kb[i2 < NANCH ? i2 : 0];
        unsigned long long k3 = kb[i3 < NANCH ? i3 : 0];
        if (k0 >= Kst) {
            unsigned int p = atomicAdd(&s_cnt, 1u);
            if (p < 2048) skeys[p] = k0;
        }
        if (i1 < NANCH && k1 >= Kst) {
            unsigned int p = atomicAdd(&s_cnt, 1u);
            if (p < 2048) skeys[p] = k1;
        }
        if (i2 < NANCH && k2 >= Kst) {
            unsigned int p = atomicAdd(&s_cnt, 1u);
            if (p < 2048) skeys[p] = k2;
        }
        if (i3 < NANCH && k3 >= Kst) {
            unsigned int p = atomicAdd(&s_cnt, 1u);
            if (p < 2048) skeys[p] = k3;
        }
    }
    __syncthreads();
    unsigned int cnt = s_cnt;
    for (int i = t; i < 2048; i += 1024)
        if (i >= (int)cnt) skeys[i] = 0ull;
    for (int k = 2; k <= 2048; k <<= 1) {
        for (int j = k >> 1; j > 0; j >>= 1) {
            __syncthreads();
            for (int i = t; i < 2048; i += 1024) {
                int l = i ^ j;
                if (l > i) {
                    unsigned long long a = skeys[i], c = skeys[l];
                    bool up = ((i & k) == 0);
                    if (up ? (a < c) : (a > c)) { skeys[i] = c; skeys[l] = a; }
                }
            }
        }
    }
    __syncthreads();
    for (int i = t; i < PRE_N; i += 1024) {
        unsigned long long k = skeys[i];
        unsigned int k32 = (unsigned int)(k >> 15);
        float m = (k32 & 0x80000000u) ? __uint_as_float(k32 & 0x7FFFFFFFu)
                                      : __uint_as_float(~k32);
        unsigned int idx = 32767u - (unsigned int)(k & 32767ull);
        size_t gi = (size_t)b * NANCH + idx;
        top_s[b * PRE_N + i] = m;
        ((float4*)top_boxes)[b * PRE_N + i] = ((const float4*)boxes)[gi];
    }
}

// ---------------- IoU suppression bit-matrix ----------------
__global__ __launch_bounds__(256) void sup_kernel(const float* __restrict__ top_boxes,
                                                  unsigned long long* __restrict__ supm) {
    int blk = blockIdx.x;
    int b = blk / 125;
    int chunk = blk % 125;
    int t = threadIdx.x;

    __shared__ float bx1[PRE_N], by1[PRE_N], bx2[PRE_N], by2[PRE_N];
    for (int i = t; i < PRE_N; i += 256) {
        float4 v = ((const float4*)top_boxes)[b * PRE_N + i];
        bx1[i] = v.x; by1[i] = v.y; bx2[i] = v.z; by2[i] = v.w;
    }
    __syncthreads();

    int wave = t >> 6, lane = t & 63;
    for (int rr = 0; rr < 4; ++rr) {
        int i = chunk * 16 + wave * 4 + rr;
        float ax1 = bx1[i], ay1 = by1[i], ax2 = bx2[i], ay2 = by2[i];
        float aarea = (ax2 - ax1) * (ay2 - ay1);
        for (int jw = 0; jw < 32; ++jw) {
            int j = jw * 64 + lane;
            bool sup = false;
            if (j > i && j < PRE_N) {
                float jx1 = bx1[j], jy1 = by1[j], jx2 = bx2[j], jy2 = by2[j];
                float ix1 = fmaxf(ax1, jx1), iy1 = fmaxf(ay1, jy1);
                float ix2 = fminf(ax2, jx2), iy2 = fminf(ay2, jy2);
                float iw = fmaxf(ix2 - ix1, 0.f);
                float ih = fmaxf(iy2 - iy1, 0.f);
                float inter = iw * ih;
                float barea = (jx2 - jx1) * (jy2 - jy1);
                float iou = inter / (aarea + barea - inter + 1e-9f);
                sup = iou > 0.7f;
            }
            unsigned long long m = __ballot(sup);
            if (lane == 0) supm[((size_t)b * PRE_N + i) * 32 + jw] = m;
        }
    }
}

// ---------------- fused: tiled NMS scan (wave 0) + stable top-100 finalize ----------------
__global__ __launch_bounds__(256) void nms_fin_kernel(const float* __restrict__ top_s,
                                                      const unsigned long long* __restrict__ supm,
                                                      const float* __restrict__ top_boxes,
                                                      float* __restrict__ out) {
    int b = blockIdx.x;
    int t = threadIdx.x;
    __shared__ unsigned int kw[64];
    __shared__ int wpre[65];

    if (t < 64) {
        int lane = t;
        unsigned int alive = 0;
        const float* ts = top_s + (size_t)b * PRE_N + lane * 32;
#pragma unroll
        for (int q4 = 0; q4 < 8; ++q4) {
            float4 v = *(const float4*)&ts[q4 * 4];
            int base = lane * 32 + q4 * 4;
            if (base + 0 < PRE_N && v.x > 0.f) alive |= 1u << (q4 * 4 + 0);
            if (base + 1 < PRE_N && v.y > 0.f) alive |= 1u << (q4 * 4 + 1);
            if (base + 2 < PRE_N && v.z > 0.f) alive |= 1u << (q4 * 4 + 2);
            if (base + 3 < PRE_N && v.w > 0.f) alive |= 1u << (q4 * 4 + 3);
        }
        const unsigned long long* sm = supm + (size_t)b * PRE_N * 32;
        const unsigned int* sup32 = (const unsigned int*)sm;

        for (int tt = 0; tt < 32; ++tt) {
            unsigned int alo = __shfl(alive, 2 * tt);
            unsigned int ahi = __shfl(alive, 2 * tt + 1);
            unsigned long long talive = (unsigned long long)alo | ((unsigned long long)ahi << 32);
            int i_row = tt * 64 + lane;
            unsigned long long rm = (i_row < PRE_N) ? sm[(size_t)i_row * 32 + tt] : 0ull;

            unsigned long long kept = 0, rem = talive;
            while (rem) {
                int j = __builtin_ctzll(rem);
                kept |= (1ull << j);
                unsigned long long rmj = __shfl(rm, j);
                rem &= ~rmj;
                rem &= ~(1ull << j);
            }

            // 8-wide OR-accumulation: 8 independent loads per latency round
            unsigned int oracc = 0;
            unsigned long long kk = kept;
            while (kk) {
                int j0 = __builtin_ctzll(kk); kk &= kk - 1;
                int j1 = -1, j2 = -1, j3 = -1, j4 = -1, j5 = -1, j6 = -1, j7 = -1;
                if (kk) { j1 = __builtin_ctzll(kk); kk &= kk - 1; }
                if (kk) { j2 = __builtin_ctzll(kk); kk &= kk - 1; }
                if (kk) { j3 = __builtin_ctzll(kk); kk &= kk - 1; }
                if (kk) { j4 = __builtin_ctzll(kk); kk &= kk - 1; }
                if (kk) { j5 = __builtin_ctzll(kk); kk &= kk - 1; }
                if (kk) { j6 = __builtin_ctzll(kk); kk &= kk - 1; }
                if (kk) { j7 = __builtin_ctzll(kk); kk &= kk - 1; }
                unsigned int v0 = sup32[(size_t)(tt * 64 + j0) * 64 + lane];
                unsigned int v1 = (j1 >= 0) ? sup32[(size_t)(tt * 64 + j1) * 64 + lane] : 0u;
                unsigned int v2 = (j2 >= 0) ? sup32[(size_t)(tt * 64 + j2) * 64 + lane] : 0u;
                unsigned int v3 = (j3 >= 0) ? sup32[(size_t)(tt * 64 + j3) * 64 + lane] : 0u;
                unsigned int v4 = (j4 >= 0) ? sup32[(size_t)(tt * 64 + j4) * 64 + lane] : 0u;
                unsigned int v5 = (j5 >= 0) ? sup32[(size_t)(tt * 64 + j5) * 64 + lane] : 0u;
                unsigned int v6 = (j6 >= 0) ? sup32[(size_t)(tt * 64 + j6) * 64 + lane] : 0u;
                unsigned int v7 = (j7 >= 0) ? sup32[(size_t)(tt * 64 + j7) * 64 + lane] : 0u;
                oracc |= (v0 | v1) | (v2 | v3) | (v4 | v5) | (v6 | v7);
            }
            alive &= ~oracc;
            if (lane == 2 * tt)     alive = (unsigned int)kept;
            if (lane == 2 * tt + 1) alive = (unsigned int)(kept >> 32);
        }
        kw[lane] = alive;
    }
    __syncthreads();
    if (t == 0) {
        int run = 0;
        for (int w = 0; w < 64; ++w) { wpre[w] = run; run += __popc(kw[w]); }
        wpre[64] = run;
    }
    __syncthreads();
    int total = wpre[64];
    float* out_boxes  = out;
    float* out_scores = out + NB * POST_N * 4;
    for (int i = t; i < PRE_N; i += 256) {
        unsigned int w = kw[i >> 5];
        bool kept = (w >> (i & 31)) & 1u;
        int rk = wpre[i >> 5] + __popc(w & ((1u << (i & 31)) - 1u));
        int pos = kept ? rk : total + (i - rk);
        if (pos < POST_N) {
            out_scores[b * POST_N + pos] = kept ? top_s[b * PRE_N + i] : -1.0f;
            ((float4*)out_boxes)[b * POST_N + pos] = ((const float4*)top_boxes)[b * PRE_N + i];
        }
    }
}

// ---------------- launch ----------------
extern "C" void kernel_launch(void* const* d_in, const int* in_sizes, int n_in,
                              void* d_out, int out_size, void* d_ws, size_t ws_size,
                              hipStream_t stream) {
    const float* features = (const float*)d_in[0];
    const float* W1 = (const float*)d_in[1];
    const float* b1 = (const float*)d_in[2];
    const float* W2 = (const float*)d_in[3];
    const float* b2 = (const float*)d_in[4];
    const float* W3 = (const float*)d_in[5];
    const float* b3 = (const float*)d_in[6];
    float* out = (float*)d_out;
    char* ws = (char*)d_ws;

    unsigned short* Tph = (unsigned short*)(ws + OFF_TPH);
    unsigned short* Tpl = (unsigned short*)(ws + OFF_TPL);
    float* boxes   = (float*)(ws + OFF_BOXES);
    unsigned long long* keys = (unsigned long long*)(ws + OFF_KEYS);
    float* top_boxes = (float*)(ws + OFF_TBOX);
    float* top_s     = (float*)(ws + OFF_TS);
    unsigned long long* supm = (unsigned long long*)(ws + OFF_SUP);
    unsigned short* FPh = (unsigned short*)(ws + OFF_PH);
    unsigned short* FPl = (unsigned short*)(ws + OFF_PL);
    unsigned short* WPh = (unsigned short*)(ws + OFF_WH);
    unsigned short* WPl = (unsigned short*)(ws + OFF_WL);
    unsigned short* W23h = (unsigned short*)(ws + OFF_W23H);
    unsigned short* W23l = (unsigned short*)(ws + OFF_W23L);

    static bool conv_attr_set = false;
    if (!conv_attr_set) {
        hipFuncSetAttribute(reinterpret_cast<const void*>(&conv_mfma),
                            hipFuncAttributeMaxDynamicSharedMemorySize, 73728);
        conv_attr_set = true;
    }

    prep_all<<<6088, 256, 0, stream>>>(features, W1, W2, W3, FPh, FPl, WPh, WPl, W23h, W23l);
    conv_mfma<<<704, 256, 73728, stream>>>(FPh, FPl, WPh, WPl, b1, Tph, Tpl);
    proj_decode_mfma<<<157, 256, 0, stream>>>(Tph, Tpl, W23h, W23l, b2, b3, boxes, keys);
    select_sort_kernel<<<NB, 1024, 0, stream>>>(keys, boxes, top_boxes, top_s);
    sup_kernel<<<NB * 125, 256, 0, stream>>>(top_boxes, supm);
    nms_fin_kernel<<<NB, 256, 0, stream>>>(top_s, supm, top_boxes, out);
}